// Round 1
// baseline (794.904 us; speedup 1.0000x reference)
//
#include <hip/hip_runtime.h>

#define N_NODES 50000
#define N_EDGES 800000
#define IN_DIM 128
#define OUT_DIM 64

// ---------------------------------------------------------------------------
// Phase 1: support = x @ weight   (fp32 vector-ALU GEMM; no fp32 MFMA on CDNA4)
// weight (128x64 = 32 KB) staged in LDS; 16 nodes per block iteration,
// 16 threads per node, 4 consecutive outputs per thread (float4 LDS reads).
// x rows staged in LDS padded to 129 floats to avoid 4-way bank conflicts
// (stride 128 floats = same bank for all 4 node-groups in a wave).
// ---------------------------------------------------------------------------
__global__ __launch_bounds__(256) void gemm_kernel(const float* __restrict__ x,
                                                   const float* __restrict__ w,
                                                   float* __restrict__ support) {
    __shared__ float w_lds[IN_DIM * OUT_DIM];   // 32 KB
    __shared__ float x_lds[16 * (IN_DIM + 1)];  // ~8 KB, +1 pad breaks bank aliasing

    for (int i = threadIdx.x; i < IN_DIM * OUT_DIM; i += 256)
        w_lds[i] = w[i];

    const int lane  = threadIdx.x & 15;   // output group: 4 outputs starting at lane*4
    const int local = threadIdx.x >> 4;   // node slot within block, 0..15

    for (int node_base = blockIdx.x * 16; node_base < N_NODES;
         node_base += gridDim.x * 16) {
        __syncthreads();  // also covers first-iteration w_lds visibility
        // stage 16 rows of x (2048 floats, 8 per thread), coalesced
        for (int i = threadIdx.x; i < 16 * IN_DIM; i += 256) {
            int node = node_base + (i >> 7);
            int k    = i & 127;
            x_lds[(i >> 7) * (IN_DIM + 1) + k] =
                (node < N_NODES) ? x[(size_t)node * IN_DIM + k] : 0.0f;
        }
        __syncthreads();

        int node = node_base + local;
        if (node < N_NODES) {
            float acc0 = 0.f, acc1 = 0.f, acc2 = 0.f, acc3 = 0.f;
            const float* xr = &x_lds[local * (IN_DIM + 1)];
            #pragma unroll 8
            for (int k = 0; k < IN_DIM; ++k) {
                float  xv = xr[k];
                float4 wv = *(const float4*)&w_lds[k * OUT_DIM + lane * 4];
                acc0 += xv * wv.x;
                acc1 += xv * wv.y;
                acc2 += xv * wv.z;
                acc3 += xv * wv.w;
            }
            float4 o = make_float4(acc0, acc1, acc2, acc3);
            *(float4*)&support[(size_t)node * OUT_DIM + lane * 4] = o;
        }
    }
}

// ---------------------------------------------------------------------------
// Phase 2: scatter-add messages.  16 threads per edge; thread g reads one
// float4 of support[col[e]] (256 B contiguous per edge) and atomically adds
// val[e]*s into out[row[e]].  atomicAdd on global is device-scope (XCD-safe).
// ---------------------------------------------------------------------------
__global__ __launch_bounds__(256) void scatter_kernel(const int* __restrict__ erow,
                                                      const int* __restrict__ ecol,
                                                      const float* __restrict__ eval,
                                                      const float* __restrict__ support,
                                                      float* __restrict__ out) {
    long long t = (long long)blockIdx.x * 256 + threadIdx.x;
    const long long total = (long long)N_EDGES * 16;
    if (t >= total) return;
    int e = (int)(t >> 4);
    int g = (int)(t & 15);
    int r = erow[e];
    int c = ecol[e];
    float v = eval[e];
    float4 s = *(const float4*)&support[(size_t)c * OUT_DIM + g * 4];
    float* o = &out[(size_t)r * OUT_DIM + g * 4];
    atomicAdd(o + 0, v * s.x);
    atomicAdd(o + 1, v * s.y);
    atomicAdd(o + 2, v * s.z);
    atomicAdd(o + 3, v * s.w);
}

// ---------------------------------------------------------------------------
// Phase 3: in-place ReLU on the accumulated output.
// ---------------------------------------------------------------------------
__global__ __launch_bounds__(256) void relu_kernel(float* __restrict__ out, int n4) {
    int t = blockIdx.x * 256 + threadIdx.x;
    if (t >= n4) return;
    float4* p = (float4*)out + t;
    float4 v = *p;
    v.x = fmaxf(v.x, 0.f);
    v.y = fmaxf(v.y, 0.f);
    v.z = fmaxf(v.z, 0.f);
    v.w = fmaxf(v.w, 0.f);
    *p = v;
}

extern "C" void kernel_launch(void* const* d_in, const int* in_sizes, int n_in,
                              void* d_out, int out_size, void* d_ws, size_t ws_size,
                              hipStream_t stream) {
    const float* x    = (const float*)d_in[0];
    const int*   erow = (const int*)  d_in[1];
    const int*   ecol = (const int*)  d_in[2];
    const float* ev   = (const float*)d_in[3];
    const float* w    = (const float*)d_in[4];
    float* out     = (float*)d_out;
    float* support = (float*)d_ws;   // 50000*64 fp32 = 12.8 MB scratch

    // out accumulates via atomics -> must start at zero (harness poisons 0xAA)
    hipMemsetAsync(d_out, 0, sizeof(float) * (size_t)N_NODES * OUT_DIM, stream);

    gemm_kernel<<<(N_NODES + 15) / 16, 256, 0, stream>>>(x, w, support);

    long long sc_threads = (long long)N_EDGES * 16;
    scatter_kernel<<<(int)((sc_threads + 255) / 256), 256, 0, stream>>>(
        erow, ecol, ev, support, out);

    int n4 = (N_NODES * OUT_DIM) / 4;
    relu_kernel<<<(n4 + 255) / 256, 256, 0, stream>>>(out, n4);
}

// Round 2
// 280.664 us; speedup vs baseline: 2.8322x; 2.8322x over previous
//
#include <hip/hip_runtime.h>

#define N_NODES 50000
#define N_EDGES 800000
#define IN_DIM 128
#define OUT_DIM 64

// ---------------------------------------------------------------------------
// Phase 1: support = x @ weight   (fp32 vector-ALU GEMM; no fp32 MFMA on CDNA4)
// ---------------------------------------------------------------------------
__global__ __launch_bounds__(256) void gemm_kernel(const float* __restrict__ x,
                                                   const float* __restrict__ w,
                                                   float* __restrict__ support) {
    __shared__ float w_lds[IN_DIM * OUT_DIM];   // 32 KB
    __shared__ float x_lds[16 * (IN_DIM + 1)];  // +1 pad breaks bank aliasing

    for (int i = threadIdx.x; i < IN_DIM * OUT_DIM; i += 256)
        w_lds[i] = w[i];

    const int lane  = threadIdx.x & 15;   // 4 outputs starting at lane*4
    const int local = threadIdx.x >> 4;   // node slot 0..15

    for (int node_base = blockIdx.x * 16; node_base < N_NODES;
         node_base += gridDim.x * 16) {
        __syncthreads();
        for (int i = threadIdx.x; i < 16 * IN_DIM; i += 256) {
            int node = node_base + (i >> 7);
            int k    = i & 127;
            x_lds[(i >> 7) * (IN_DIM + 1) + k] =
                (node < N_NODES) ? x[(size_t)node * IN_DIM + k] : 0.0f;
        }
        __syncthreads();

        int node = node_base + local;
        if (node < N_NODES) {
            float acc0 = 0.f, acc1 = 0.f, acc2 = 0.f, acc3 = 0.f;
            const float* xr = &x_lds[local * (IN_DIM + 1)];
            #pragma unroll 8
            for (int k = 0; k < IN_DIM; ++k) {
                float  xv = xr[k];
                float4 wv = *(const float4*)&w_lds[k * OUT_DIM + lane * 4];
                acc0 += xv * wv.x;
                acc1 += xv * wv.y;
                acc2 += xv * wv.z;
                acc3 += xv * wv.w;
            }
            *(float4*)&support[(size_t)node * OUT_DIM + lane * 4] =
                make_float4(acc0, acc1, acc2, acc3);
        }
    }
}

// ---------------------------------------------------------------------------
// Phase 2a: histogram of edge_row  (int atomics, 1 per edge)
// ---------------------------------------------------------------------------
__global__ __launch_bounds__(256) void hist_kernel(const int* __restrict__ erow,
                                                   int* __restrict__ cnt) {
    int e = blockIdx.x * 256 + threadIdx.x;
    if (e < N_EDGES) atomicAdd(&cnt[erow[e]], 1);
}

// ---------------------------------------------------------------------------
// Phase 2b: exclusive scan of counts -> offs (and a mutable copy -> cursor).
// Single 1024-thread block; wave-shuffle scan + 16-wave combine per chunk.
// ---------------------------------------------------------------------------
__global__ __launch_bounds__(1024) void scan_kernel(const int* __restrict__ cnt,
                                                    int* __restrict__ offs,
                                                    int* __restrict__ cursor) {
    __shared__ int wsum[16];
    __shared__ int carry_s;
    const int tid  = threadIdx.x;
    const int lane = tid & 63;
    const int wid  = tid >> 6;
    if (tid == 0) carry_s = 0;
    __syncthreads();

    for (int base = 0; base < N_NODES; base += 1024) {
        int idx = base + tid;
        int v = (idx < N_NODES) ? cnt[idx] : 0;
        // inclusive scan within wave (64 lanes)
        int s = v;
        #pragma unroll
        for (int off = 1; off < 64; off <<= 1) {
            int t = __shfl_up(s, off, 64);
            if (lane >= off) s += t;
        }
        if (lane == 63) wsum[wid] = s;
        __syncthreads();
        // scan the 16 wave totals with wave 0
        if (wid == 0 && lane < 16) {
            int wv = wsum[lane];
            #pragma unroll
            for (int off = 1; off < 16; off <<= 1) {
                int t = __shfl_up(wv, off, 64);
                if (lane >= off) wv += t;
            }
            wsum[lane] = wv;   // inclusive
        }
        __syncthreads();
        int carry = carry_s;
        int incl  = s + ((wid > 0) ? wsum[wid - 1] : 0);
        int excl  = incl - v + carry;
        if (idx < N_NODES) { offs[idx] = excl; cursor[idx] = excl; }
        __syncthreads();
        if (tid == 0) carry_s = carry + wsum[15];
        __syncthreads();
    }
}

// ---------------------------------------------------------------------------
// Phase 2c: bin edges into row-sorted buckets: bucket[p] = (col, val_bits)
// ---------------------------------------------------------------------------
__global__ __launch_bounds__(256) void fill_kernel(const int* __restrict__ erow,
                                                   const int* __restrict__ ecol,
                                                   const float* __restrict__ eval,
                                                   int* __restrict__ cursor,
                                                   int2* __restrict__ bucket) {
    int e = blockIdx.x * 256 + threadIdx.x;
    if (e >= N_EDGES) return;
    int r = erow[e];
    int p = atomicAdd(&cursor[r], 1);
    bucket[p] = make_int2(ecol[e], __float_as_int(eval[e]));
}

// ---------------------------------------------------------------------------
// Phase 3: per-row gather-reduce + fused ReLU.  16 lanes per row, each lane
// owns 4 output columns (float4).  Zero fp atomics; each output written once.
// ---------------------------------------------------------------------------
__global__ __launch_bounds__(256) void reduce_kernel(const int* __restrict__ offs,
                                                     const int2* __restrict__ bucket,
                                                     const float* __restrict__ support,
                                                     float* __restrict__ out) {
    const int g     = threadIdx.x & 15;
    const int local = threadIdx.x >> 4;
    const int row   = blockIdx.x * 16 + local;
    if (row >= N_NODES) return;
    const int start = offs[row];
    const int end   = (row == N_NODES - 1) ? N_EDGES : offs[row + 1];
    float4 acc = make_float4(0.f, 0.f, 0.f, 0.f);
    for (int j = start; j < end; ++j) {
        int2 cv = bucket[j];                       // broadcast across the 16 lanes
        float v = __int_as_float(cv.y);
        float4 s = *(const float4*)&support[(size_t)cv.x * OUT_DIM + g * 4];
        acc.x += v * s.x;
        acc.y += v * s.y;
        acc.z += v * s.z;
        acc.w += v * s.w;
    }
    acc.x = fmaxf(acc.x, 0.f);
    acc.y = fmaxf(acc.y, 0.f);
    acc.z = fmaxf(acc.z, 0.f);
    acc.w = fmaxf(acc.w, 0.f);
    *(float4*)&out[(size_t)row * OUT_DIM + g * 4] = acc;
}

extern "C" void kernel_launch(void* const* d_in, const int* in_sizes, int n_in,
                              void* d_out, int out_size, void* d_ws, size_t ws_size,
                              hipStream_t stream) {
    const float* x    = (const float*)d_in[0];
    const int*   erow = (const int*)  d_in[1];
    const int*   ecol = (const int*)  d_in[2];
    const float* ev   = (const float*)d_in[3];
    const float* w    = (const float*)d_in[4];
    float* out = (float*)d_out;

    // workspace layout (all 16B-aligned offsets)
    char*  ws      = (char*)d_ws;
    float* support = (float*)ws;                    // 12,800,000 B
    int*   cnt     = (int*)(ws + 12800000);         //    200,000 B
    int*   offs    = (int*)(ws + 13000000);         //    200,000 B
    int*   cursor  = (int*)(ws + 13200000);         //    200,000 B
    int2*  bucket  = (int2*)(ws + 13400000);        //  6,400,000 B  (tot 19.8 MB)

    hipMemsetAsync(cnt, 0, sizeof(int) * N_NODES, stream);

    gemm_kernel<<<(N_NODES + 15) / 16, 256, 0, stream>>>(x, w, support);

    hist_kernel<<<(N_EDGES + 255) / 256, 256, 0, stream>>>(erow, cnt);
    scan_kernel<<<1, 1024, 0, stream>>>(cnt, offs, cursor);
    fill_kernel<<<(N_EDGES + 255) / 256, 256, 0, stream>>>(erow, ecol, ev, cursor, bucket);
    reduce_kernel<<<(N_NODES + 15) / 16, 256, 0, stream>>>(offs, bucket, support, out);
}

// Round 3
// 233.634 us; speedup vs baseline: 3.4024x; 1.2013x over previous
//
#include <hip/hip_runtime.h>

#define N_NODES 50000
#define N_EDGES 800000
#define IN_DIM 128
#define OUT_DIM 64
#define SCAN_BLOCKS 49   // ceil(50000/1024)

// bf16 helpers (support is stored bf16 to halve gather traffic; accum stays fp32)
static __device__ __forceinline__ unsigned short f2bf(float f) {
    unsigned u = __float_as_uint(f);
    unsigned r = u + 0x7fff + ((u >> 16) & 1);   // round-to-nearest-even
    return (unsigned short)(r >> 16);
}
static __device__ __forceinline__ float bf2f(unsigned short b) {
    return __uint_as_float((unsigned)b << 16);
}

// ---------------------------------------------------------------------------
// Phase 1: support = x @ weight  (fp32 VALU GEMM, bf16 store)
// ---------------------------------------------------------------------------
__global__ __launch_bounds__(256) void gemm_kernel(const float* __restrict__ x,
                                                   const float* __restrict__ w,
                                                   unsigned short* __restrict__ support) {
    __shared__ float w_lds[IN_DIM * OUT_DIM];   // 32 KB
    __shared__ float x_lds[16 * (IN_DIM + 1)];

    for (int i = threadIdx.x; i < IN_DIM * OUT_DIM; i += 256)
        w_lds[i] = w[i];

    const int lane  = threadIdx.x & 15;
    const int local = threadIdx.x >> 4;

    for (int node_base = blockIdx.x * 16; node_base < N_NODES;
         node_base += gridDim.x * 16) {
        __syncthreads();
        for (int i = threadIdx.x; i < 16 * IN_DIM; i += 256) {
            int node = node_base + (i >> 7);
            int k    = i & 127;
            x_lds[(i >> 7) * (IN_DIM + 1) + k] =
                (node < N_NODES) ? x[(size_t)node * IN_DIM + k] : 0.0f;
        }
        __syncthreads();

        int node = node_base + local;
        if (node < N_NODES) {
            float acc0 = 0.f, acc1 = 0.f, acc2 = 0.f, acc3 = 0.f;
            const float* xr = &x_lds[local * (IN_DIM + 1)];
            #pragma unroll 8
            for (int k = 0; k < IN_DIM; ++k) {
                float  xv = xr[k];
                float4 wv = *(const float4*)&w_lds[k * OUT_DIM + lane * 4];
                acc0 += xv * wv.x;
                acc1 += xv * wv.y;
                acc2 += xv * wv.z;
                acc3 += xv * wv.w;
            }
            ushort4 o;
            o.x = f2bf(acc0); o.y = f2bf(acc1); o.z = f2bf(acc2); o.w = f2bf(acc3);
            *(ushort4*)&support[(size_t)node * OUT_DIM + lane * 4] = o;
        }
    }
}

// ---------------------------------------------------------------------------
// Phase 2a: histogram of edge_row
// ---------------------------------------------------------------------------
__global__ __launch_bounds__(256) void hist_kernel(const int* __restrict__ erow,
                                                   int* __restrict__ cnt) {
    int e = blockIdx.x * 256 + threadIdx.x;
    if (e < N_EDGES) atomicAdd(&cnt[erow[e]], 1);
}

// ---------------------------------------------------------------------------
// Phase 2b: three-kernel device-wide exclusive scan (replaces 51 us 1-block scan)
// ---------------------------------------------------------------------------
__global__ __launch_bounds__(1024) void scan_a(const int* __restrict__ cnt,
                                               int* __restrict__ excl,
                                               int* __restrict__ btot) {
    __shared__ int wsum[16];
    const int tid  = threadIdx.x;
    const int lane = tid & 63;
    const int wid  = tid >> 6;
    int idx = blockIdx.x * 1024 + tid;
    int v = (idx < N_NODES) ? cnt[idx] : 0;
    int s = v;
    #pragma unroll
    for (int off = 1; off < 64; off <<= 1) {
        int t = __shfl_up(s, off, 64);
        if (lane >= off) s += t;
    }
    if (lane == 63) wsum[wid] = s;
    __syncthreads();
    if (wid == 0 && lane < 16) {
        int wv = wsum[lane];
        #pragma unroll
        for (int off = 1; off < 16; off <<= 1) {
            int t = __shfl_up(wv, off, 64);
            if (lane >= off) wv += t;
        }
        wsum[lane] = wv;
    }
    __syncthreads();
    int excl_v = s - v + ((wid > 0) ? wsum[wid - 1] : 0);
    if (idx < N_NODES) excl[idx] = excl_v;
    if (tid == 1023) btot[blockIdx.x] = excl_v + v;   // block total
}

__global__ __launch_bounds__(64) void scan_b(const int* __restrict__ btot,
                                             int* __restrict__ bbase) {
    int lane = threadIdx.x;
    int v = (lane < SCAN_BLOCKS) ? btot[lane] : 0;
    int s = v;
    #pragma unroll
    for (int off = 1; off < 64; off <<= 1) {
        int t = __shfl_up(s, off, 64);
        if (lane >= off) s += t;
    }
    if (lane < SCAN_BLOCKS) bbase[lane] = s - v;
}

__global__ __launch_bounds__(1024) void scan_c(int* __restrict__ excl,
                                               const int* __restrict__ bbase,
                                               int* __restrict__ offs,
                                               int* __restrict__ cursor) {
    int idx = blockIdx.x * 1024 + threadIdx.x;
    if (idx < N_NODES) {
        int o = excl[idx] + bbase[blockIdx.x];
        offs[idx]   = o;
        cursor[idx] = o;
    }
}

// ---------------------------------------------------------------------------
// Phase 2c: bin edges into row-sorted buckets
// ---------------------------------------------------------------------------
__global__ __launch_bounds__(256) void fill_kernel(const int* __restrict__ erow,
                                                   const int* __restrict__ ecol,
                                                   const float* __restrict__ eval,
                                                   int* __restrict__ cursor,
                                                   int2* __restrict__ bucket) {
    int e = blockIdx.x * 256 + threadIdx.x;
    if (e >= N_EDGES) return;
    int r = erow[e];
    int p = atomicAdd(&cursor[r], 1);
    bucket[p] = make_int2(ecol[e], __float_as_int(eval[e]));
}

// ---------------------------------------------------------------------------
// Phase 3: per-row gather-reduce + fused ReLU (support is bf16)
// ---------------------------------------------------------------------------
__global__ __launch_bounds__(256) void reduce_kernel(const int* __restrict__ offs,
                                                     const int2* __restrict__ bucket,
                                                     const unsigned short* __restrict__ support,
                                                     float* __restrict__ out) {
    const int g     = threadIdx.x & 15;
    const int local = threadIdx.x >> 4;
    const int row   = blockIdx.x * 16 + local;
    if (row >= N_NODES) return;
    const int start = offs[row];
    const int end   = (row == N_NODES - 1) ? N_EDGES : offs[row + 1];
    float4 acc = make_float4(0.f, 0.f, 0.f, 0.f);
    for (int j = start; j < end; ++j) {
        int2 cv = bucket[j];
        float v = __int_as_float(cv.y);
        ushort4 sr = *(const ushort4*)&support[(size_t)cv.x * OUT_DIM + g * 4];
        acc.x += v * bf2f(sr.x);
        acc.y += v * bf2f(sr.y);
        acc.z += v * bf2f(sr.z);
        acc.w += v * bf2f(sr.w);
    }
    acc.x = fmaxf(acc.x, 0.f);
    acc.y = fmaxf(acc.y, 0.f);
    acc.z = fmaxf(acc.z, 0.f);
    acc.w = fmaxf(acc.w, 0.f);
    *(float4*)&out[(size_t)row * OUT_DIM + g * 4] = acc;
}

extern "C" void kernel_launch(void* const* d_in, const int* in_sizes, int n_in,
                              void* d_out, int out_size, void* d_ws, size_t ws_size,
                              hipStream_t stream) {
    const float* x    = (const float*)d_in[0];
    const int*   erow = (const int*)  d_in[1];
    const int*   ecol = (const int*)  d_in[2];
    const float* ev   = (const float*)d_in[3];
    const float* w    = (const float*)d_in[4];
    float* out = (float*)d_out;

    // workspace layout (16B-aligned offsets)
    char* ws = (char*)d_ws;
    unsigned short* support = (unsigned short*)ws;       // 6,400,000 B
    int*  cnt    = (int*)(ws +  6400000);                //   200,000 B
    int*  excl   = (int*)(ws +  6600000);                //   200,000 B
    int*  offs   = (int*)(ws +  6800000);                //   200,000 B
    int*  cursor = (int*)(ws +  7000000);                //   200,000 B
    int*  btot   = (int*)(ws +  7200000);                //       256 B
    int*  bbase  = (int*)(ws +  7200512);                //       256 B
    int2* bucket = (int2*)(ws + 7201024);                // 6,400,000 B (tot ~13.6 MB)

    hipMemsetAsync(cnt, 0, sizeof(int) * N_NODES, stream);

    gemm_kernel<<<(N_NODES + 15) / 16, 256, 0, stream>>>(x, w, support);

    hist_kernel<<<(N_EDGES + 255) / 256, 256, 0, stream>>>(erow, cnt);
    scan_a<<<SCAN_BLOCKS, 1024, 0, stream>>>(cnt, excl, btot);
    scan_b<<<1, 64, 0, stream>>>(btot, bbase);
    scan_c<<<SCAN_BLOCKS, 1024, 0, stream>>>(excl, bbase, offs, cursor);
    fill_kernel<<<(N_EDGES + 255) / 256, 256, 0, stream>>>(erow, ecol, ev, cursor, bucket);
    reduce_kernel<<<(N_NODES + 15) / 16, 256, 0, stream>>>(offs, bucket, support, out);
}